// Round 1
// 346.275 us; speedup vs baseline: 1.0185x; 1.0185x over previous
//
#include <hip/hip_runtime.h>
#include <math.h>
#include <stdint.h>

// image_batch (32,1,512,512) f32, angles (8,) f32 -> out (32,8,512,512) f32
#define N_IMG 32
#define N_ANG 8
#define H_ 512
#define W_ 512

// Output tile 64x32. Rotated source footprint <= ~71 px/axis; with floor/ceil
// margins (+3), 4-alignment (-3) and the 1-row/4-col derived-tap margin the
// staged bbox is <= 76 rows x <= 81 cols. LDS layout: pitch 84 words
// (bank stride 84%32=20 -> good spread), 25 chunks of 256 words = 6400 words
// = 25.6 KB per buffer. DOUBLE-BUFFERED (2x25.6 = 51.2 KB) -> 3 blocks/CU by
// LDS; staging of image n+1 overlaps compute of image n (T3 2-phase pipeline).
#define TX 64
#define TY 32
#define LP 84
#define NCHUNK 25
#define LWORDS (NCHUNK * 256)

__global__ __launch_bounds__(256, 3) void rotate_tile_kernel(
    const float* __restrict__ img,     // [N_IMG][H][W]
    const float* __restrict__ angles,  // [N_ANG] degrees
    float* __restrict__ out)           // [N_IMG][N_ANG][H][W]
{
    __shared__ float tile[2 * LWORDS];

    const int bz   = blockIdx.z;
    const int k    = bz >> 1;                  // angle
    const int n0   = (bz & 1) * (N_IMG / 2);   // image half
    const int tx0  = blockIdx.x * TX;
    const int ty0  = blockIdx.y * TY;
    const int tid  = threadIdx.x;
    const int wid  = tid >> 6;
    const int lane = tid & 63;

    const float rad = angles[k] * 0.017453292519943295f;
    float sa, ca;
    sincosf(rad, &sa, &ca);
    const float cx = (W_ - 1) * 0.5f;
    const float cy = (H_ - 1) * 0.5f;

    // ---- source bbox (block-uniform) from the 4 tile corners ----
    float minsx = 1e30f, maxsx = -1e30f, minsy = 1e30f, maxsy = -1e30f;
#pragma unroll
    for (int cyi = 0; cyi < 2; ++cyi) {
#pragma unroll
        for (int cxi = 0; cxi < 2; ++cxi) {
            const float xr = (float)(tx0 + cxi * (TX - 1)) - cx;
            const float yr = (float)(ty0 + cyi * (TY - 1)) - cy;
            const float sx = ca * xr - sa * yr + cx;
            const float sy = sa * xr + ca * yr + cy;
            minsx = fminf(minsx, sx); maxsx = fmaxf(maxsx, sx);
            minsy = fminf(minsy, sy); maxsy = fmaxf(maxsy, sy);
        }
    }
    const int bx0 = min(max((int)floorf(minsx) - 1, 0), W_ - 1);
    const int by0 = min(max((int)floorf(minsy) - 1, 0), H_ - 1);
    // margined origins: one extra staged row and 4-col group at top/left so
    // taps x1=x0+1 / y1=y0+1 are always base+1 / base+LP (derived offsets
    // stay exact at the image boundary).
    const int bx0m = (bx0 & ~3) - 4;   // multiple of 4 (possibly negative)
    const int by0m = by0 - 1;

    // ---- per-lane staging source offsets: computed ONCE, reused 16 images.
    // Flat LDS word f -> (row,col) with pitch 84 (col stays mult-of-4, so a
    // lane's 16B never crosses an LDS row). Global side clamped in-bounds;
    // clamped (garbage) words are only ever gathered with weight 0.
    int goff[7];
    int nst = 0;
    for (int s = wid; s < NCHUNK; s += 4) {
        const int f   = s * 256 + lane * 4;
        const int row = f / LP;
        const int col = f - row * LP;
        const int grow = min(max(by0m + row, 0), H_ - 1);
        const int gcol = min(max(bx0m + col, 0), W_ - 4);
        goff[nst++] = grow * W_ + gcol;
    }

    // ---- lane -> output-pixel mapping, chosen per angle to spread LDS banks:
    // lanes along x when |cos|>=|sin| (near-horizontal source rows), along y
    // otherwise. Block-uniform -> no divergence.
    const bool modeA = fabsf(ca) >= fabsf(sa);
    const int pxg = modeA ? (tid & 15) : (tid >> 4);
    const int py0 = modeA ? (tid >> 4) : (tid & 15);
    const int px  = pxg * 4;

    // ---- per-pixel base LDS offset + 4 bilinear weights (image-independent)
    int   ob[2][4];
    float w00[2][4], w01[2][4], w10[2][4], w11[2][4];
#pragma unroll
    for (int p = 0; p < 2; ++p) {
        const int   yy = ty0 + py0 + p * 16;
        const float yr = (float)yy - cy;
#pragma unroll
        for (int j = 0; j < 4; ++j) {
            const int   xx = tx0 + px + j;
            const float xr = (float)xx - cx;
            const float sxs = ca * xr - sa * yr + cx;
            const float sys = sa * xr + ca * yr + cy;
            const float x0f = floorf(sxs), y0f = floorf(sys);
            const float wx = sxs - x0f, wy = sys - y0f;
            const int x0 = (int)x0f, y0 = (int)y0f;
            const bool vx0 = ((unsigned)x0       < (unsigned)W_);
            const bool vx1 = ((unsigned)(x0 + 1) < (unsigned)W_);
            const bool vy0 = ((unsigned)y0       < (unsigned)H_);
            const bool vy1 = ((unsigned)(y0 + 1) < (unsigned)H_);
            // valid taps are never clamped (margins guarantee range);
            // clamping only keeps weight-0 taps inside the LDS array.
            const int lx = min(max(x0 - bx0m, 0), 82);
            const int ly = min(max(y0 - by0m, 0), 74);
            ob[p][j] = ly * LP + lx;
            const float omwx = 1.0f - wx, omwy = 1.0f - wy;
            w00[p][j] = omwy * omwx * (float)(vy0 && vx0);
            w01[p][j] = omwy * wx   * (float)(vy0 && vx1);
            w10[p][j] = wy   * omwx * (float)(vy1 && vx0);
            w11[p][j] = wy   * wx   * (float)(vy1 && vx1);
        }
    }

    // ---- staging helper: issue this wave's chunks of image n into buffer b.
    auto stage_img = [&](int n, int b) {
        const float* __restrict__ ib = img + (size_t)n * (H_ * W_);
        float* dst0 = &tile[b * LWORDS];
        for (int i = 0; i < nst; ++i) {
            __builtin_amdgcn_global_load_lds(
                (const __attribute__((address_space(1))) void*)(ib + goff[i]),
                (__attribute__((address_space(3))) void*)(dst0 + (wid + i * 4) * 256),
                16, 0, 0);
        }
    };

    // ---- 2-phase pipeline over the 16 images:
    //   prologue: stage img0 -> buf0; vmcnt(0); barrier
    //   iter n:   issue stage img n+1 -> buf^1   (overlaps with...)
    //             compute img n from buf, store
    //             vmcnt(2); barrier              (drain prefetch loads only —
    //                                             the 2 newest VMEM ops are
    //                                             this image's stores, left
    //                                             in flight)
    // Hazards: buf^1 was last READ in iter n-1's compute -> protected by the
    // barrier at end of iter n-1. buf's staging loads (issued iter n-1) are
    // drained by that same vmcnt+barrier before any wave reads them.
    stage_img(n0, 0);
    asm volatile("s_waitcnt vmcnt(0)" ::: "memory");
    __builtin_amdgcn_s_barrier();

    int cur = 0;
    for (int idx = 0; idx < N_IMG / 2; ++idx) {
        const int n = n0 + idx;
        const bool more = (idx + 1 < N_IMG / 2);
        if (more) {
            stage_img(n + 1, cur ^ 1);
            // pin issue order: [prefetch loads][ds_reads -> stores] so the
            // counted vmcnt(2) below always drains exactly the loads.
            __builtin_amdgcn_sched_barrier(0);
        }

        const float* __restrict__ tb = &tile[cur * LWORDS];
        float* __restrict__ outn =
            out + ((size_t)(n * N_ANG + k) * H_ + ty0) * W_ + tx0;
#pragma unroll
        for (int p = 0; p < 2; ++p) {
            float v[4];
#pragma unroll
            for (int j = 0; j < 4; ++j) {
                const float* __restrict__ b0 = &tb[ob[p][j]];
                // taps: (y0,x0)=b0[0], (y0,x1)=b0[1], (y1,x0)=b0[LP], (y1,x1)=b0[LP+1]
                v[j] = w00[p][j] * b0[0]
                     + w01[p][j] * b0[1]
                     + w10[p][j] * b0[LP]
                     + w11[p][j] * b0[LP + 1];
            }
            float4* dst = (float4*)(outn + (py0 + p * 16) * W_ + px);
            *dst = make_float4(v[0], v[1], v[2], v[3]);
        }

        if (more) {
            // Drain the prefetch loads (oldest in flight); leave this image's
            // 2 output stores (newest) in flight — their ack latency stays
            // off the critical path. Previous iter's stores are older than
            // these loads, so they drain here too: count is always correct.
            asm volatile("s_waitcnt vmcnt(2)" ::: "memory");
            __builtin_amdgcn_s_barrier();
            cur ^= 1;
        }
    }
}

extern "C" void kernel_launch(void* const* d_in, const int* in_sizes, int n_in,
                              void* d_out, int out_size, void* d_ws, size_t ws_size,
                              hipStream_t stream) {
    const float* img    = (const float*)d_in[0];
    const float* angles = (const float*)d_in[1];
    float* out          = (float*)d_out;

    dim3 block(256, 1, 1);
    dim3 grid(W_ / TX, H_ / TY, N_ANG * 2);  // 8 x 16 x 16 = 2048 blocks
    rotate_tile_kernel<<<grid, block, 0, stream>>>(img, angles, out);
}

// Round 2
// 339.258 us; speedup vs baseline: 1.0395x; 1.0207x over previous
//
#include <hip/hip_runtime.h>
#include <math.h>
#include <stdint.h>

// image_batch (32,1,512,512) f32, angles (8,) f32 -> out (32,8,512,512) f32
#define N_IMG 32
#define N_ANG 8
#define H_ 512
#define W_ 512

// Output tile 64x32. Rotated source footprint <= ~71 px/axis; with floor/ceil
// margins (+3), 4-alignment (-3) and the 1-row/4-col derived-tap margin the
// staged bbox is <= 76 rows x <= 81 cols. LDS layout: pitch 84 words
// (bank stride 84%32=20 -> good spread), 25 chunks of 256 words = 6400 words
// = 25.6 KB per buffer. DOUBLE-BUFFERED (2x25.6 = 51.2 KB) -> 3 blocks/CU by
// LDS; staging of image n+1 overlaps compute of image n (T3 2-phase pipeline).
#define TX 64
#define TY 32
#define LP 84
#define NCHUNK 25
#define LWORDS (NCHUNK * 256)
// modeB out-stage pitch (transpose buffer reuses the consumed gather buffer):
// 32 rows x 68 words = 2176 words (8.7 KB) << LWORDS. 68%32=4 -> wave64
// b128 accesses hit every bank exactly 8x = conflict-free minimum.
#define OP 68

__global__ __launch_bounds__(256, 3) void rotate_tile_kernel(
    const float* __restrict__ img,     // [N_IMG][H][W]
    const float* __restrict__ angles,  // [N_ANG] degrees
    float* __restrict__ out)           // [N_IMG][N_ANG][H][W]
{
    __shared__ float tile[2 * LWORDS];

    const int bz   = blockIdx.z;
    const int k    = bz >> 1;                  // angle
    const int n0   = (bz & 1) * (N_IMG / 2);   // image half
    const int tx0  = blockIdx.x * TX;
    const int ty0  = blockIdx.y * TY;
    const int tid  = threadIdx.x;
    const int wid  = tid >> 6;
    const int lane = tid & 63;

    const float rad = angles[k] * 0.017453292519943295f;
    float sa, ca;
    sincosf(rad, &sa, &ca);
    const float cx = (W_ - 1) * 0.5f;
    const float cy = (H_ - 1) * 0.5f;

    // ---- source bbox (block-uniform) from the 4 tile corners ----
    float minsx = 1e30f, maxsx = -1e30f, minsy = 1e30f, maxsy = -1e30f;
#pragma unroll
    for (int cyi = 0; cyi < 2; ++cyi) {
#pragma unroll
        for (int cxi = 0; cxi < 2; ++cxi) {
            const float xr = (float)(tx0 + cxi * (TX - 1)) - cx;
            const float yr = (float)(ty0 + cyi * (TY - 1)) - cy;
            const float sx = ca * xr - sa * yr + cx;
            const float sy = sa * xr + ca * yr + cy;
            minsx = fminf(minsx, sx); maxsx = fmaxf(maxsx, sx);
            minsy = fminf(minsy, sy); maxsy = fmaxf(maxsy, sy);
        }
    }
    const int bx0 = min(max((int)floorf(minsx) - 1, 0), W_ - 1);
    const int by0 = min(max((int)floorf(minsy) - 1, 0), H_ - 1);
    // margined origins: one extra staged row and 4-col group at top/left so
    // taps x1=x0+1 / y1=y0+1 are always base+1 / base+LP (derived offsets
    // stay exact at the image boundary).
    const int bx0m = (bx0 & ~3) - 4;   // multiple of 4 (possibly negative)
    const int by0m = by0 - 1;

    // ---- per-lane staging source offsets: computed ONCE, reused 16 images.
    // Flat LDS word f -> (row,col) with pitch 84 (col stays mult-of-4, so a
    // lane's 16B never crosses an LDS row). Global side clamped in-bounds;
    // clamped (garbage) words are only ever gathered with weight 0.
    int goff[7];
    int nst = 0;
    for (int s = wid; s < NCHUNK; s += 4) {
        const int f   = s * 256 + lane * 4;
        const int row = f / LP;
        const int col = f - row * LP;
        const int grow = min(max(by0m + row, 0), H_ - 1);
        const int gcol = min(max(bx0m + col, 0), W_ - 4);
        goff[nst++] = grow * W_ + gcol;
    }

    // ---- lane -> output-pixel mapping, chosen per angle to spread LDS banks:
    // lanes along x when |cos|>=|sin| (near-horizontal source rows), along y
    // otherwise. Block-uniform -> no divergence. NOTE: modeB's mapping is
    // gather-only; its global stores go through an LDS transpose (below) so
    // the HBM write pattern is always 256-B-contiguous runs.
    const bool modeA = fabsf(ca) >= fabsf(sa);
    const int pxg = modeA ? (tid & 15) : (tid >> 4);
    const int py0 = modeA ? (tid >> 4) : (tid & 15);
    const int px  = pxg * 4;

    // ---- per-pixel base LDS offset + 4 bilinear weights (image-independent)
    int   ob[2][4];
    float w00[2][4], w01[2][4], w10[2][4], w11[2][4];
#pragma unroll
    for (int p = 0; p < 2; ++p) {
        const int   yy = ty0 + py0 + p * 16;
        const float yr = (float)yy - cy;
#pragma unroll
        for (int j = 0; j < 4; ++j) {
            const int   xx = tx0 + px + j;
            const float xr = (float)xx - cx;
            const float sxs = ca * xr - sa * yr + cx;
            const float sys = sa * xr + ca * yr + cy;
            const float x0f = floorf(sxs), y0f = floorf(sys);
            const float wx = sxs - x0f, wy = sys - y0f;
            const int x0 = (int)x0f, y0 = (int)y0f;
            const bool vx0 = ((unsigned)x0       < (unsigned)W_);
            const bool vx1 = ((unsigned)(x0 + 1) < (unsigned)W_);
            const bool vy0 = ((unsigned)y0       < (unsigned)H_);
            const bool vy1 = ((unsigned)(y0 + 1) < (unsigned)H_);
            // valid taps are never clamped (margins guarantee range);
            // clamping only keeps weight-0 taps inside the LDS array.
            const int lx = min(max(x0 - bx0m, 0), 82);
            const int ly = min(max(y0 - by0m, 0), 74);
            ob[p][j] = ly * LP + lx;
            const float omwx = 1.0f - wx, omwy = 1.0f - wy;
            w00[p][j] = omwy * omwx * (float)(vy0 && vx0);
            w01[p][j] = omwy * wx   * (float)(vy0 && vx1);
            w10[p][j] = wy   * omwx * (float)(vy1 && vx0);
            w11[p][j] = wy   * wx   * (float)(vy1 && vx1);
        }
    }

    // ---- staging helper: issue this wave's chunks of image n into buffer b.
    auto stage_img = [&](int n, int b) {
        const float* __restrict__ ib = img + (size_t)n * (H_ * W_);
        float* dst0 = &tile[b * LWORDS];
        for (int i = 0; i < nst; ++i) {
            __builtin_amdgcn_global_load_lds(
                (const __attribute__((address_space(1))) void*)(ib + goff[i]),
                (__attribute__((address_space(3))) void*)(dst0 + (wid + i * 4) * 256),
                16, 0, 0);
        }
    };

    // ---- 2-phase pipeline over the 16 images (T3 minimum recipe):
    //   prologue: stage img0 -> buf0; vmcnt(0); barrier
    //   iter n:   issue stage img n+1 -> buf^1   (overlaps with...)
    //             compute img n from buf; store (modeB: via LDS transpose)
    //             vmcnt(2); barrier              (drain prefetch loads only —
    //                                             the 2 newest VMEM ops are
    //                                             this image's stores, left
    //                                             in flight)
    stage_img(n0, 0);
    asm volatile("s_waitcnt vmcnt(0)" ::: "memory");
    __builtin_amdgcn_s_barrier();

    int cur = 0;
    for (int idx = 0; idx < N_IMG / 2; ++idx) {
        const int n = n0 + idx;
        const bool more = (idx + 1 < N_IMG / 2);
        if (more) {
            stage_img(n + 1, cur ^ 1);
            // pin issue order: [prefetch loads][compute -> stores] so the
            // counted vmcnt(2) below always drains exactly the loads.
            __builtin_amdgcn_sched_barrier(0);
        }

        const float* __restrict__ tb = &tile[cur * LWORDS];
        float* __restrict__ outn =
            out + ((size_t)(n * N_ANG + k) * H_ + ty0) * W_ + tx0;

        // gather ALL taps first (both p) so modeB can repurpose tb afterward
        float v[2][4];
#pragma unroll
        for (int p = 0; p < 2; ++p) {
#pragma unroll
            for (int j = 0; j < 4; ++j) {
                const float* __restrict__ b0 = &tb[ob[p][j]];
                // taps: (y0,x0)=b0[0], (y0,x1)=b0[1], (y1,x0)=b0[LP], (y1,x1)=b0[LP+1]
                v[p][j] = w00[p][j] * b0[0]
                        + w01[p][j] * b0[1]
                        + w10[p][j] * b0[LP]
                        + w11[p][j] * b0[LP + 1];
            }
        }

        if (modeA) {
            // lanes already span x: 16 lanes x 16B = 256-B contiguous runs.
#pragma unroll
            for (int p = 0; p < 2; ++p) {
                float4* dst = (float4*)(outn + (py0 + p * 16) * W_ + px);
                *dst = make_float4(v[p][0], v[p][1], v[p][2], v[p][3]);
            }
        } else {
            // modeB: lanes span y -> direct stores would be 16-B scatters at
            // 2-KB stride (4x HBM write amplification). Transpose through the
            // just-consumed gather buffer, then store coalesced.
            // barrier: every wave's v[] is in registers => all ds_reads of tb
            // retired => tb is safe to clobber. Raw s_barrier (no vmcnt drain
            // -- prefetch stays in flight).
            __builtin_amdgcn_s_barrier();
            float* __restrict__ os = (float*)&tile[cur * LWORDS];
#pragma unroll
            for (int p = 0; p < 2; ++p) {
                float4* d = (float4*)(os + (py0 + p * 16) * OP + px);
                *d = make_float4(v[p][0], v[p][1], v[p][2], v[p][3]);
            }
            // drain own ds_writes (lgkm only!), then barrier: transposed tile
            // visible to all waves. sched_barrier pins the ds_reads below
            // after the wait (rule #18).
            asm volatile("s_waitcnt lgkmcnt(0)" ::: "memory");
            __builtin_amdgcn_sched_barrier(0);
            __builtin_amdgcn_s_barrier();
            const int rx = (tid & 15) * 4;   // coalesced mapping (modeA-style)
            const int ry = tid >> 4;
#pragma unroll
            for (int p = 0; p < 2; ++p) {
                float4 t = *(float4*)(os + (ry + p * 16) * OP + rx);
                *(float4*)(outn + (ry + p * 16) * W_ + rx) = t;
            }
        }

        if (more) {
            // Drain the prefetch loads (oldest in flight); leave this image's
            // 2 output stores (newest) in flight — their ack latency stays
            // off the critical path.
            asm volatile("s_waitcnt vmcnt(2)" ::: "memory");
            __builtin_amdgcn_s_barrier();
            cur ^= 1;
        }
    }
}

extern "C" void kernel_launch(void* const* d_in, const int* in_sizes, int n_in,
                              void* d_out, int out_size, void* d_ws, size_t ws_size,
                              hipStream_t stream) {
    const float* img    = (const float*)d_in[0];
    const float* angles = (const float*)d_in[1];
    float* out          = (float*)d_out;

    dim3 block(256, 1, 1);
    dim3 grid(W_ / TX, H_ / TY, N_ANG * 2);  // 8 x 16 x 16 = 2048 blocks
    rotate_tile_kernel<<<grid, block, 0, stream>>>(img, angles, out);
}